// Round 3
// baseline (215.694 us; speedup 1.0000x reference)
//
#include <hip/hip_runtime.h>
#include <hip/hip_bf16.h>
#include <stdint.h>

#define TKS    4096   // tokens = 2*2048
#define KD     4096   // in_features
#define NSF    410    // split_f
#define NPARTS 10
#define OUTF   4096

typedef unsigned short u16;
typedef __attribute__((ext_vector_type(8))) short bf16x8;
typedef __attribute__((ext_vector_type(4))) float f32x4;

// ---- workspace layout (sx/gc carved from unused bsw slabs 448..511) ----
#define WS_XB  0                                     // u16[4096*4096]  granule bf16 x (32-row tiles)
#define WS_BSW ((size_t)TKS * KD * 2)                // u16[512*4096]   granule bf16 Wfc (64-row tiles)
#define WS_SX  (WS_BSW + (size_t)448 * 512 * 8 * 2)  // f32[4096*10]    sx
#define WS_GC  (WS_SX + (size_t)TKS * NPARTS * 4)    // f32[448*12]     G (cols 0..9) + c (col 10)
#define WS_WSL (WS_BSW + (size_t)512 * KD * 2)       // u16[16*4096]    granule bf16 Wsel
#define WS_WEX (WS_WSL + (size_t)16 * KD * 2)        // u16[16*4096]    granule bf16 Wexp^T (+bexp row 10)

__device__ inline u16 f2bf(float f) {
    union { __hip_bfloat16 b; u16 u; } cv;
    cv.b = __float2bfloat16(f);
    return cv.u;
}

// 64-row tile granule g in [0,512): slot=g>>6 = hi*4+ks*2+lo
// row = hi*32+lo*16+(g&15) ; col = ks*32+((g>>4)&3)*8   (conflict-free, proven)
__device__ inline int g_row(int g) { int s = g >> 6; return (s >> 2) * 32 + (s & 1) * 16 + (g & 15); }
__device__ inline int g_col(int g) { int s = g >> 6; return ((s >> 1) & 1) * 32 + ((g >> 4) & 3) * 8; }

// ============ prep_w: Wsel/Wexp -> 16-row granule-tiled bf16 (unchanged) =====
__global__ __launch_bounds__(256) void prep_w(const float* __restrict__ Wsel,
                                              const float* __restrict__ Wexp,
                                              const float* __restrict__ bexp,
                                              u16* __restrict__ wselb,
                                              u16* __restrict__ wexpb) {
    const int kt = blockIdx.x;           // 0..63
    const int tid = threadIdx.x;
    const int g  = tid & 127;
    const int ml = g & 15;
    const int col = kt * 64 + (g >> 6) * 32 + ((g >> 4) & 3) * 8;
    u16 h[8];
    if (tid < 128) {
#pragma unroll
        for (int j = 0; j < 8; ++j)
            h[j] = (ml < NPARTS) ? f2bf(Wsel[(size_t)ml * KD + col + j]) : (u16)0;
        *(uint4*)&wselb[((size_t)kt * 128 + g) * 8] = *(uint4*)h;
    } else {
#pragma unroll
        for (int j = 0; j < 8; ++j)
            h[j] = (ml < NPARTS) ? f2bf(Wexp[(size_t)(col + j) * NPARTS + ml])
                 : (ml == NPARTS ? f2bf(bexp[col + j]) : (u16)0);
        *(uint4*)&wexpb[((size_t)kt * 128 + g) * 8] = *(uint4*)h;
    }
}

// ============ retile_b: Wfc (f32) -> bsw (bf16 granule-tiled) (unchanged) ====
__global__ __launch_bounds__(256) void retile_b(const float* __restrict__ Wfc,
                                                u16* __restrict__ bsw) {
    const int kt = blockIdx.x & 63, rb = blockIdx.x >> 6;
    const int tid = threadIdx.x;
    u16* tout = bsw + ((size_t)(rb * 64 + kt) * 512) * 8;
#pragma unroll
    for (int j = 0; j < 2; ++j) {
        const int g = j * 256 + tid;
        const int r = rb * 64 + g_row(g);
        uint4 pk = make_uint4(0u, 0u, 0u, 0u);
        if (r < NSF) {
            const float* src = Wfc + (size_t)r * KD + kt * 64 + g_col(g);
            float4 v0 = *(const float4*)src;
            float4 v1 = *(const float4*)(src + 4);
            u16 h[8] = { f2bf(v0.x), f2bf(v0.y), f2bf(v0.z), f2bf(v0.w),
                         f2bf(v1.x), f2bf(v1.y), f2bf(v1.z), f2bf(v1.w) };
            pk = *(uint4*)h;
        }
        *(uint4*)&tout[(size_t)g * 8] = pk;
    }
}

// ============ retile_x: x (f32) -> xb (bf16, 32-row granule tiles) (unchanged)
__global__ __launch_bounds__(256) void retile_x(const float* __restrict__ x,
                                                u16* __restrict__ xb) {
    const int kt = blockIdx.x & 63, tb = blockIdx.x >> 6;   // tb 0..127
    const int g = threadIdx.x;                              // granule 0..255
    const int slot = g >> 6;                                // ks*2+lo
    const int row = (slot & 1) * 16 + (g & 15);
    const int col = (slot >> 1) * 32 + ((g >> 4) & 3) * 8;
    const float* src = x + (size_t)(tb * 32 + row) * KD + kt * 64 + col;
    float4 v0 = *(const float4*)src;
    float4 v1 = *(const float4*)(src + 4);
    u16 h[8] = { f2bf(v0.x), f2bf(v0.y), f2bf(v0.z), f2bf(v0.w),
                 f2bf(v1.x), f2bf(v1.y), f2bf(v1.z), f2bf(v1.w) };
    *(uint4*)&xb[((size_t)(tb * 64 + kt) * 256 + g) * 8] = *(uint4*)h;
}

// ============ sel_g: hoisted sx = x*Wsel^T + bsel  and  Gc = [Wfc*Wexp | c] ==
// grid 135: blocks 0..127 -> sx (32 tokens each); 128..134 -> G/c (64 f each).
// Direct global->reg fragment loads (granule layouts proven in old main loop).
__global__ __launch_bounds__(256) void sel_g(const u16* __restrict__ xb,
                                             const u16* __restrict__ bsw,
                                             const u16* __restrict__ wselb,
                                             const u16* __restrict__ wexpb,
                                             const float* __restrict__ bsel,
                                             const float* __restrict__ bfc,
                                             float* __restrict__ sxb,
                                             float* __restrict__ gc) {
    __shared__ float lred[4][64][16];   // 16 KB cross-wave reduce
    const int tid = threadIdx.x, lane = tid & 63, w = tid >> 6;
    const int q = lane >> 4, ml = lane & 15;
    const int b = blockIdx.x;

    if (b < 128) {
        // sx for tokens b*32 .. b*32+31 ; wave w covers kt in [w*16, w*16+16)
        f32x4 a0 = (f32x4){0.f,0.f,0.f,0.f}, a1 = (f32x4){0.f,0.f,0.f,0.f};
        for (int kt = w * 16; kt < w * 16 + 16; ++kt) {
#pragma unroll
            for (int ks = 0; ks < 2; ++ks) {
                bf16x8 wl  = *(const bf16x8*)&wselb[((size_t)kt * 128 + ks * 64 + lane) * 8];
                bf16x8 av0 = *(const bf16x8*)&xb[(((size_t)b * 64 + kt) * 256 + (ks * 2 + 0) * 64 + lane) * 8];
                bf16x8 av1 = *(const bf16x8*)&xb[(((size_t)b * 64 + kt) * 256 + (ks * 2 + 1) * 64 + lane) * 8];
                a0 = __builtin_amdgcn_mfma_f32_16x16x32_bf16(av0, wl, a0, 0, 0, 0);
                a1 = __builtin_amdgcn_mfma_f32_16x16x32_bf16(av1, wl, a1, 0, 0, 0);
            }
        }
#pragma unroll
        for (int r = 0; r < 4; ++r) {
            lred[w][q * 4 + r][ml]      = a0[r];
            lred[w][16 + q * 4 + r][ml] = a1[r];
        }
        __syncthreads();
        for (int i = tid; i < 32 * NPARTS; i += 256) {
            const int t = i / NPARTS, n = i % NPARTS;
            sxb[((size_t)b * 32 + t) * NPARTS + n] =
                lred[0][t][n] + lred[1][t][n] + lred[2][t][n] + lred[3][t][n] + bsel[n];
        }
    } else {
        const int fb = b - 128;          // 0..6, f rows fb*64 .. +63
        f32x4 g0 = (f32x4){0.f,0.f,0.f,0.f}, g1 = g0, g2 = g0, g3 = g0;
        for (int kt = w * 16; kt < w * 16 + 16; ++kt) {
#pragma unroll
            for (int ks = 0; ks < 2; ++ks) {
                bf16x8 ef = *(const bf16x8*)&wexpb[((size_t)kt * 128 + ks * 64 + lane) * 8];
                bf16x8 b0 = *(const bf16x8*)&bsw[(((size_t)fb * 64 + kt) * 512 + (0 * 4 + ks * 2 + 0) * 64 + lane) * 8];
                bf16x8 b1 = *(const bf16x8*)&bsw[(((size_t)fb * 64 + kt) * 512 + (0 * 4 + ks * 2 + 1) * 64 + lane) * 8];
                bf16x8 b2 = *(const bf16x8*)&bsw[(((size_t)fb * 64 + kt) * 512 + (1 * 4 + ks * 2 + 0) * 64 + lane) * 8];
                bf16x8 b3 = *(const bf16x8*)&bsw[(((size_t)fb * 64 + kt) * 512 + (1 * 4 + ks * 2 + 1) * 64 + lane) * 8];
                g0 = __builtin_amdgcn_mfma_f32_16x16x32_bf16(b0, ef, g0, 0, 0, 0);
                g1 = __builtin_amdgcn_mfma_f32_16x16x32_bf16(b1, ef, g1, 0, 0, 0);
                g2 = __builtin_amdgcn_mfma_f32_16x16x32_bf16(b2, ef, g2, 0, 0, 0);
                g3 = __builtin_amdgcn_mfma_f32_16x16x32_bf16(b3, ef, g3, 0, 0, 0);
            }
        }
#pragma unroll
        for (int r = 0; r < 4; ++r) {
            lred[w][ 0 + q * 4 + r][ml] = g0[r];
            lred[w][16 + q * 4 + r][ml] = g1[r];
            lred[w][32 + q * 4 + r][ml] = g2[r];
            lred[w][48 + q * 4 + r][ml] = g3[r];
        }
        __syncthreads();
        for (int i = tid; i < 64 * 11; i += 256) {
            const int f = i / 11, c = i % 11;
            float s = lred[0][f][c] + lred[1][f][c] + lred[2][f][c] + lred[3][f][c];
            const int fg = fb * 64 + f;
            if (c == 10) s += (fg < NSF ? bfc[fg] : 0.f);
            gc[(size_t)fg * 12 + c] = s;
        }
    }
}

// ============ main: zero-LDS, zero-barrier K-loop, direct global->reg ========
// Tile per wave: 64 tok x 32 f, 4-way K-split (wave kh covers kt in [kh*16,kh*16+16)).
// Register blocking per 32-K step: 4 av x 2 bv -> 8 MFMA from 6 loads (0.094 B/MAC).
// grid 832 = 13 f2 x 64 tb (blockIdx = f2*64+tb: stride 64 % 8 == 0 keeps all
// f2-blocks of a given tb on one XCD -> A-slab L2 reuse). One barrier total.
#define A_IDX(kt, mi, ks) ((((size_t)(tb * 2 + ((mi) >> 1)) * 64 + (size_t)(kt)) * 256 \
                            + ((ks) * 2 + ((mi) & 1)) * 64 + lane) * 8)
#define B_IDX(kt, nj, ks) (((size_t)(fb * 64 + (kt)) * 512 \
                            + (wf * 4 + (ks) * 2 + (nj)) * 64 + lane) * 8)

__global__ __launch_bounds__(256, 4) void main_kernel(const u16* __restrict__ xb,
                                                      const u16* __restrict__ bsw,
                                                      const float* __restrict__ sxb,
                                                      const float* __restrict__ gc,
                                                      float* __restrict__ out) {
    // [mi][donor kh][row16][f pad 34]: stride 34 -> bank = (ml+8q)%32, 2-way = free
    __shared__ float red[4][4][16][34];   // 34.8 KB
    __shared__ float sxt[64][NPARTS];     // 2.5 KB
    __shared__ float gt[32][12];          // 1.5 KB

    const int tid = threadIdx.x;
    const int f2 = blockIdx.x >> 6;     // 0..12  (f2=13 would be all fg>=410)
    const int tb = blockIdx.x & 63;     // 0..63  (64-token tiles)
    const int lane = tid & 63;
    const int kh = tid >> 6;            // K-split wave id 0..3
    const int q = lane >> 4, ml = lane & 15;
    const int fb = f2 >> 1, wf = f2 & 1;

    f32x4 acc[4][2];
#pragma unroll
    for (int mi = 0; mi < 4; ++mi)
#pragma unroll
        for (int nj = 0; nj < 2; ++nj) acc[mi][nj] = (f32x4){0.f,0.f,0.f,0.f};

    bf16x8 fa[2][4], fbv[2][2];

#define LOADAB(p, kt, ks) do {                                            \
        _Pragma("unroll")                                                 \
        for (int mi = 0; mi < 4; ++mi)                                    \
            fa[p][mi] = *(const bf16x8*)&xb[A_IDX((kt), mi, (ks))];       \
        _Pragma("unroll")                                                 \
        for (int nj = 0; nj < 2; ++nj)                                    \
            fbv[p][nj] = *(const bf16x8*)&bsw[B_IDX((kt), nj, (ks))];     \
    } while (0)

#define MFMAS(p) do {                                                     \
        _Pragma("unroll")                                                 \
        for (int mi = 0; mi < 4; ++mi)                                    \
            _Pragma("unroll")                                             \
            for (int nj = 0; nj < 2; ++nj)                                \
                acc[mi][nj] = __builtin_amdgcn_mfma_f32_16x16x32_bf16(    \
                    fa[p][mi], fbv[p][nj], acc[mi][nj], 0, 0, 0);         \
    } while (0)

    // software-pipelined: buffer p computed while p^1 loads are in flight
    LOADAB(0, kh * 16, 0);
    for (int it2 = 0; it2 < 16; ++it2) {
        const int kt = kh * 16 + it2;
        LOADAB(1, kt, 1);
        MFMAS(0);
        if (it2 + 1 < 16) LOADAB(0, kt + 1, 0);
        MFMAS(1);
    }
#undef LOADAB
#undef MFMAS

    // ---- K-reduce: wave kh publishes partials; owns row group kh after barrier
#pragma unroll
    for (int mi = 0; mi < 4; ++mi)
#pragma unroll
        for (int nj = 0; nj < 2; ++nj)
#pragma unroll
            for (int r = 0; r < 4; ++r)
                red[mi][kh][q * 4 + r][nj * 16 + ml] = acc[mi][nj][r];

    // stage sx / G tables (global -> LDS) while reduce data lands
    for (int i = tid; i < 64 * NPARTS; i += 256)
        sxt[i / NPARTS][i % NPARTS] = sxb[((size_t)tb * 64 + i / NPARTS) * NPARTS + i % NPARTS];
    for (int i = tid; i < 32 * 11; i += 256)
        gt[i / 11][i % 11] = gc[((size_t)f2 * 32 + i / 11) * 12 + i % 11];
    __syncthreads();

    // ---- epilogue: wave kh stores rows kh*16 .. kh*16+15 ----
#pragma unroll
    for (int nj = 0; nj < 2; ++nj) {
        const int fl = nj * 16 + ml;
        const int fg = f2 * 32 + fl;
        if (fg >= NSF) continue;
        const float cv = gt[fl][10];
        float gv[NPARTS];
#pragma unroll
        for (int n = 0; n < NPARTS; ++n) gv[n] = gt[fl][n];
#pragma unroll
        for (int r = 0; r < 4; ++r) {
            const int tl = kh * 16 + q * 4 + r;
            const float v = red[kh][0][q * 4 + r][fl] + red[kh][1][q * 4 + r][fl]
                          + red[kh][2][q * 4 + r][fl] + red[kh][3][q * 4 + r][fl];
            const float av = v + cv;
            float* orow = out + (size_t)(tb * 64 + tl) * OUTF;
#pragma unroll
            for (int n = 0; n < NPARTS; ++n) {
                const int j = n * NSF + fg;
                if (j < OUTF) orow[j] = av + sxt[tl][n] * gv[n];
            }
        }
    }
}

extern "C" void kernel_launch(void* const* d_in, const int* in_sizes, int n_in,
                              void* d_out, int out_size, void* d_ws, size_t ws_size,
                              hipStream_t stream) {
    const float* x    = (const float*)d_in[0];
    const float* Wsel = (const float*)d_in[1];
    const float* bsel = (const float*)d_in[2];
    const float* Wexp = (const float*)d_in[3];
    const float* bexp = (const float*)d_in[4];
    const float* Wfc  = (const float*)d_in[5];
    const float* bfc  = (const float*)d_in[6];
    float* out = (float*)d_out;

    char* ws = (char*)d_ws;
    u16* xb    = (u16*)(ws + WS_XB);
    u16* bsw   = (u16*)(ws + WS_BSW);
    u16* wselb = (u16*)(ws + WS_WSL);
    u16* wexpb = (u16*)(ws + WS_WEX);
    float* sxb = (float*)(ws + WS_SX);
    float* gcv = (float*)(ws + WS_GC);

    prep_w<<<dim3(64), dim3(256), 0, stream>>>(Wsel, Wexp, bexp, wselb, wexpb);
    retile_b<<<dim3(7 * 64), dim3(256), 0, stream>>>(Wfc, bsw);
    retile_x<<<dim3(128 * 64), dim3(256), 0, stream>>>(x, xb);
    sel_g<<<dim3(135), dim3(256), 0, stream>>>(xb, bsw, wselb, wexpb, bsel, bfc, sxb, gcv);
    main_kernel<<<dim3(13 * 64), dim3(256), 0, stream>>>(xb, bsw, sxb, gcv, out);
}